// Round 1
// baseline (2532.452 us; speedup 1.0000x reference)
//
#include <hip/hip_runtime.h>

// MultiGNN: B=256, A=64 -> 16384 images of 8x15x15
// convs: 8->16 (15->13), 16->32 (13->11), 32->16 (11->9), 16->32 (9->7)
// flatten 32*7*7=1568 -> MLP 128,128,128 -> GCN over 64 agents, E=128

#define NIMG 16384

// ---------------------------------------------------------------------------
// Conv helpers
// ---------------------------------------------------------------------------
template<int CI, int CO>
__device__ inline void stage_weights(const float* __restrict__ gw,
                                     const float* __restrict__ gb,
                                     float* sW, float* sBias, int tid)
{
    constexpr int NW = CI * 9 * CO;
    // sW[r*CO + co] = gw[co*CI*9 + r]; note i == r*CO+co when co=i%CO, r=i/CO
    for (int i = tid; i < NW; i += 256) {
        int co = i & (CO - 1);
        int r  = i / CO;
        sW[i] = gw[co * (CI * 9) + r];
    }
    if (tid < CO) sBias[tid] = gb[tid];
}

template<int CI, int CO, int HI, int WI>
__device__ inline void conv_layer(const float* __restrict__ sin_,
                                  float* __restrict__ sout,
                                  const float* __restrict__ sW,
                                  const float* __restrict__ sBias,
                                  int tid)
{
    constexpr int HO = HI - 2, WO = WI - 2, P = HO * WO;
    constexpr int NCOG = CO / 4;            // 4-channel groups
    constexpr int NPC  = (P + 3) / 4;       // 4-position chunks
    constexpr int NITEM = NCOG * NPC;

    for (int item = tid; item < NITEM; item += 256) {
        const int cog = item % NCOG;        // fastest: in-reads broadcast across cog
        const int pc  = item / NCOG;
        const int pbase = pc * 4;

        int  ib[4];
        bool valid[4];
#pragma unroll
        for (int pp = 0; pp < 4; pp++) {
            int p = pbase + pp;
            valid[pp] = (p < P);
            int pq = valid[pp] ? p : 0;
            int oy = pq / WO, ox = pq % WO;
            ib[pp] = oy * WI + ox;
        }

        float acc[4][4];
#pragma unroll
        for (int pp = 0; pp < 4; pp++)
#pragma unroll
            for (int cc = 0; cc < 4; cc++) acc[pp][cc] = sBias[cog * 4 + cc];

        for (int ci = 0; ci < CI; ci++) {
            const float* ip = sin_ + ci * (HI * WI);
            const float* wp = sW + ci * 9 * CO + cog * 4;
#pragma unroll
            for (int ky = 0; ky < 3; ky++) {
#pragma unroll
                for (int kx = 0; kx < 3; kx++) {
                    const float4 w = *(const float4*)(wp + (ky * 3 + kx) * CO);
                    const int off = ky * WI + kx;
                    float iv0 = ip[ib[0] + off];
                    float iv1 = ip[ib[1] + off];
                    float iv2 = ip[ib[2] + off];
                    float iv3 = ip[ib[3] + off];
                    acc[0][0] += iv0 * w.x; acc[0][1] += iv0 * w.y;
                    acc[0][2] += iv0 * w.z; acc[0][3] += iv0 * w.w;
                    acc[1][0] += iv1 * w.x; acc[1][1] += iv1 * w.y;
                    acc[1][2] += iv1 * w.z; acc[1][3] += iv1 * w.w;
                    acc[2][0] += iv2 * w.x; acc[2][1] += iv2 * w.y;
                    acc[2][2] += iv2 * w.z; acc[2][3] += iv2 * w.w;
                    acc[3][0] += iv3 * w.x; acc[3][1] += iv3 * w.y;
                    acc[3][2] += iv3 * w.z; acc[3][3] += iv3 * w.w;
                }
            }
        }

#pragma unroll
        for (int pp = 0; pp < 4; pp++) {
            if (!valid[pp]) continue;
            int p = pbase + pp;
#pragma unroll
            for (int cc = 0; cc < 4; cc++)
                sout[(cog * 4 + cc) * P + p] = fmaxf(acc[pp][cc], 0.0f);
        }
    }
}

__global__ __launch_bounds__(256) void conv_stack(
    const float* __restrict__ states,
    const float* __restrict__ cw0, const float* __restrict__ cb0,
    const float* __restrict__ cw1, const float* __restrict__ cb1,
    const float* __restrict__ cw2, const float* __restrict__ cb2,
    const float* __restrict__ cw3, const float* __restrict__ cb3,
    float* __restrict__ x0)
{
    __shared__ float sA[3872];   // input(1800) / L1 out(3872) / L3 out(1568)
    __shared__ float sB[2704];   // L0 out(2704) / L2 out(1296)
    __shared__ float sW[4608];
    __shared__ float sBias[32];

    const int tid = threadIdx.x;
    const int img = blockIdx.x;

    // stage input (coalesced) + L0 weights
    const float* gin = states + (size_t)img * 1800;
    for (int i = tid; i < 1800; i += 256) sA[i] = gin[i];
    stage_weights<8, 16>(cw0, cb0, sW, sBias, tid);
    __syncthreads();

    conv_layer<8, 16, 15, 15>(sA, sB, sW, sBias, tid);
    __syncthreads();
    stage_weights<16, 32>(cw1, cb1, sW, sBias, tid);
    __syncthreads();

    conv_layer<16, 32, 13, 13>(sB, sA, sW, sBias, tid);
    __syncthreads();
    stage_weights<32, 16>(cw2, cb2, sW, sBias, tid);
    __syncthreads();

    conv_layer<32, 16, 11, 11>(sA, sB, sW, sBias, tid);
    __syncthreads();
    stage_weights<16, 32>(cw3, cb3, sW, sBias, tid);
    __syncthreads();

    conv_layer<16, 32, 9, 9>(sB, sA, sW, sBias, tid);
    __syncthreads();

    // coalesced copy-out of flattened [32][7][7] = 1568
    float* gout = x0 + (size_t)img * 1568;
    for (int i = tid; i < 1568; i += 256) gout[i] = sA[i];
}

// ---------------------------------------------------------------------------
// GEMM: C[M x 128] = A[M x K] @ W[K x 128] (+bias)(+relu); M-tile 64
// ---------------------------------------------------------------------------
template<int K, bool RELU>
__global__ __launch_bounds__(256) void gemm128(
    const float* __restrict__ Am, const float* __restrict__ Wm,
    const float* __restrict__ bias, float* __restrict__ Cm)
{
    __shared__ float As[64 * 36];    // pad 32->36 keeps 16B alignment
    __shared__ float Ws[32 * 128];

    const int tid = threadIdx.x;
    const int m0  = blockIdx.x * 64;
    const int rg  = tid >> 4;        // 0..15 row group (4 rows)
    const int cg  = tid & 15;        // 0..15 col group (8 cols)

    float acc[4][8];
#pragma unroll
    for (int r = 0; r < 4; r++)
#pragma unroll
        for (int c = 0; c < 8; c++) acc[r][c] = 0.0f;

    for (int k0 = 0; k0 < K; k0 += 32) {
        __syncthreads();
        // stage A tile: 64 rows x 32 k  (float4, coalesced)
#pragma unroll
        for (int it = 0; it < 2; it++) {
            int idx = tid + it * 256;          // 0..511
            int row = idx >> 3;
            int c4  = idx & 7;
            float4 v = *(const float4*)(Am + (size_t)(m0 + row) * K + k0 + c4 * 4);
            *(float4*)(As + row * 36 + c4 * 4) = v;
        }
        // stage W tile: 32 k x 128
#pragma unroll
        for (int it = 0; it < 4; it++) {
            int idx = tid + it * 256;          // 0..1023
            int kr  = idx >> 5;
            int c4  = idx & 31;
            float4 v = *(const float4*)(Wm + (size_t)(k0 + kr) * 128 + c4 * 4);
            *(float4*)(Ws + kr * 128 + c4 * 4) = v;
        }
        __syncthreads();

#pragma unroll
        for (int kk = 0; kk < 32; kk++) {
            float a0 = As[(rg * 4 + 0) * 36 + kk];
            float a1 = As[(rg * 4 + 1) * 36 + kk];
            float a2 = As[(rg * 4 + 2) * 36 + kk];
            float a3 = As[(rg * 4 + 3) * 36 + kk];
            float4 w0 = *(const float4*)(Ws + kk * 128 + cg * 8);
            float4 w1 = *(const float4*)(Ws + kk * 128 + cg * 8 + 4);
            acc[0][0] += a0 * w0.x; acc[0][1] += a0 * w0.y; acc[0][2] += a0 * w0.z; acc[0][3] += a0 * w0.w;
            acc[0][4] += a0 * w1.x; acc[0][5] += a0 * w1.y; acc[0][6] += a0 * w1.z; acc[0][7] += a0 * w1.w;
            acc[1][0] += a1 * w0.x; acc[1][1] += a1 * w0.y; acc[1][2] += a1 * w0.z; acc[1][3] += a1 * w0.w;
            acc[1][4] += a1 * w1.x; acc[1][5] += a1 * w1.y; acc[1][6] += a1 * w1.z; acc[1][7] += a1 * w1.w;
            acc[2][0] += a2 * w0.x; acc[2][1] += a2 * w0.y; acc[2][2] += a2 * w0.z; acc[2][3] += a2 * w0.w;
            acc[2][4] += a2 * w1.x; acc[2][5] += a2 * w1.y; acc[2][6] += a2 * w1.z; acc[2][7] += a2 * w1.w;
            acc[3][0] += a3 * w0.x; acc[3][1] += a3 * w0.y; acc[3][2] += a3 * w0.z; acc[3][3] += a3 * w0.w;
            acc[3][4] += a3 * w1.x; acc[3][5] += a3 * w1.y; acc[3][6] += a3 * w1.z; acc[3][7] += a3 * w1.w;
        }
    }

#pragma unroll
    for (int r = 0; r < 4; r++) {
        int row = m0 + rg * 4 + r;
        float v[8];
#pragma unroll
        for (int c = 0; c < 8; c++) {
            float x = acc[r][c];
            if (bias) x += bias[cg * 8 + c];
            if (RELU) x = fmaxf(x, 0.0f);
            v[c] = x;
        }
        float* gp = Cm + (size_t)row * 128 + cg * 8;
        *(float4*)(gp)     = make_float4(v[0], v[1], v[2], v[3]);
        *(float4*)(gp + 4) = make_float4(v[4], v[5], v[6], v[7]);
    }
}

// ---------------------------------------------------------------------------
// GCN aggregation: out[b,j] = dinv_j * sum_i (adj[b,i,j]*dinv_i*xw[b,i]) + gb
// ---------------------------------------------------------------------------
__global__ __launch_bounds__(256) void gcn_agg(
    const float* __restrict__ adj, const float* __restrict__ xw,
    const float* __restrict__ gb, float* __restrict__ outp)
{
    __shared__ float sAdj[64 * 64];
    __shared__ float sXW[64 * 128];
    __shared__ float sDinv[64];

    const int b = blockIdx.x;
    const int tid = threadIdx.x;

    const float* ga = adj + (size_t)b * 4096;
#pragma unroll
    for (int it = 0; it < 4; it++) {
        int idx = tid + it * 256;
        *(float4*)(sAdj + idx * 4) = *(const float4*)(ga + idx * 4);
    }
    const float* gx = xw + (size_t)b * 8192;
#pragma unroll
    for (int it = 0; it < 8; it++) {
        int idx = tid + it * 256;
        *(float4*)(sXW + idx * 4) = *(const float4*)(gx + idx * 4);
    }
    __syncthreads();

    if (tid < 64) {
        float d = 0.0f;
        for (int i = 0; i < 64; i++) d += sAdj[i * 64 + tid];
        sDinv[tid] = (d > 0.0f) ? rsqrtf(d) : 0.0f;
    }
    __syncthreads();

    // fold dinv_i into xw rows
#pragma unroll
    for (int it = 0; it < 8; it++) {
        int idx = tid + it * 256;   // float4 index
        int i = idx >> 5;
        float s = sDinv[i];
        float4 v = *(float4*)(sXW + idx * 4);
        v.x *= s; v.y *= s; v.z *= s; v.w *= s;
        *(float4*)(sXW + idx * 4) = v;
    }
    __syncthreads();

    const int j  = tid >> 2;
    const int eb = (tid & 3) * 32;
    float acc[32];
#pragma unroll
    for (int e = 0; e < 32; e++) acc[e] = 0.0f;

    for (int i = 0; i < 64; i++) {
        float wgt = sAdj[i * 64 + j];
        const float* xp = sXW + i * 128 + eb;
#pragma unroll
        for (int e4 = 0; e4 < 8; e4++) {
            float4 v = *(const float4*)(xp + e4 * 4);
            acc[e4 * 4 + 0] += wgt * v.x;
            acc[e4 * 4 + 1] += wgt * v.y;
            acc[e4 * 4 + 2] += wgt * v.z;
            acc[e4 * 4 + 3] += wgt * v.w;
        }
    }

    const float dj = sDinv[j];
    float* go = outp + ((size_t)b * 64 + j) * 128 + eb;
#pragma unroll
    for (int e4 = 0; e4 < 8; e4++) {
        float4 v;
        v.x = acc[e4 * 4 + 0] * dj + gb[eb + e4 * 4 + 0];
        v.y = acc[e4 * 4 + 1] * dj + gb[eb + e4 * 4 + 1];
        v.z = acc[e4 * 4 + 2] * dj + gb[eb + e4 * 4 + 2];
        v.w = acc[e4 * 4 + 3] * dj + gb[eb + e4 * 4 + 3];
        *(float4*)(go + e4 * 4) = v;
    }
}

// ---------------------------------------------------------------------------
extern "C" void kernel_launch(void* const* d_in, const int* in_sizes, int n_in,
                              void* d_out, int out_size, void* d_ws, size_t ws_size,
                              hipStream_t stream)
{
    const float* states = (const float*)d_in[0];
    const float* adj    = (const float*)d_in[1];
    const float* cw0 = (const float*)d_in[2];  const float* cb0 = (const float*)d_in[3];
    const float* cw1 = (const float*)d_in[4];  const float* cb1 = (const float*)d_in[5];
    const float* cw2 = (const float*)d_in[6];  const float* cb2 = (const float*)d_in[7];
    const float* cw3 = (const float*)d_in[8];  const float* cb3 = (const float*)d_in[9];
    const float* mw0 = (const float*)d_in[10]; const float* mb0 = (const float*)d_in[11];
    const float* mw1 = (const float*)d_in[12]; const float* mb1 = (const float*)d_in[13];
    const float* mw2 = (const float*)d_in[14]; const float* mb2 = (const float*)d_in[15];
    const float* gw  = (const float*)d_in[16]; const float* gb  = (const float*)d_in[17];

    float* ws = (float*)d_ws;
    float* X0 = ws;                                   // 16384*1568 = 25,690,112 floats
    float* Bu = ws + (size_t)25690112;                // 16384*128
    float* Cu = Bu + (size_t)2097152;                 // 16384*128

    float* out = (float*)d_out;

    conv_stack<<<NIMG, 256, 0, stream>>>(states, cw0, cb0, cw1, cb1, cw2, cb2,
                                         cw3, cb3, X0);
    gemm128<1568, true ><<<256, 256, 0, stream>>>(X0, mw0, mb0, Bu);   // H1
    gemm128<128,  true ><<<256, 256, 0, stream>>>(Bu, mw1, mb1, Cu);   // H2
    gemm128<128,  false><<<256, 256, 0, stream>>>(Cu, mw2, mb2, Bu);   // feats
    gemm128<128,  false><<<256, 256, 0, stream>>>(Bu, gw, nullptr, Cu);// xw
    gcn_agg<<<256, 256, 0, stream>>>(adj, Cu, gb, out);
}

// Round 3
// 1177.844 us; speedup vs baseline: 2.1501x; 2.1501x over previous
//
#include <hip/hip_runtime.h>

// MultiGNN: B=256, A=64 -> 16384 images of 8x15x15
// convs: 8->16 (15->13), 16->32 (13->11), 32->16 (11->9), 16->32 (9->7)
// flatten 32*7*7=1568 -> MLP 128,128,128 -> GCN over 64 agents, E=128

#define NIMG 16384

// ---------------------------------------------------------------------------
// One-time weight transpose: wt[l][r][co] = cw[l][co][r], r = ci*9+ky*3+kx
// ---------------------------------------------------------------------------
__global__ __launch_bounds__(256) void transpose_w(
    const float* __restrict__ c0, const float* __restrict__ c1,
    const float* __restrict__ c2, const float* __restrict__ c3,
    float* __restrict__ w0, float* __restrict__ w1,
    float* __restrict__ w2, float* __restrict__ w3)
{
    int g = blockIdx.x * 256 + threadIdx.x;
    const float* src; float* dst; int CI9, CO, loc;
    if (g < 1152)       { src = c0; dst = w0; CI9 = 72;  CO = 16; loc = g; }
    else if (g < 5760)  { src = c1; dst = w1; CI9 = 144; CO = 32; loc = g - 1152; }
    else if (g < 10368) { src = c2; dst = w2; CI9 = 288; CO = 16; loc = g - 5760; }
    else if (g < 14976) { src = c3; dst = w3; CI9 = 144; CO = 32; loc = g - 10368; }
    else return;
    int r = loc / CO, co = loc - r * CO;
    dst[loc] = src[co * CI9 + r];
}

// ---------------------------------------------------------------------------
// Conv layer, 2 images per block, weights read from global (L1-cached,
// broadcast across lanes sharing cog). PC positions x 4 channels per item.
// ---------------------------------------------------------------------------
template<int CI, int CO, int HI, int WI, int PC>
__device__ __forceinline__ void conv_layer2(
    const float* __restrict__ sin0, const float* __restrict__ sin1,
    float* __restrict__ sout0, float* __restrict__ sout1,
    const float* __restrict__ wt,     // [CI*9][CO]
    const float* __restrict__ bias, int tid)
{
    constexpr int HO = HI - 2, WO = WI - 2, P = HO * WO;
    constexpr int NCOG = CO / 4;
    constexpr int NPC  = (P + PC - 1) / PC;
    constexpr int NIT  = NCOG * NPC;

    for (int item = tid; item < 2 * NIT; item += 256) {
        const bool im1 = item >= NIT;
        const int it   = im1 ? item - NIT : item;
        const float* __restrict__ sin_ = im1 ? sin1 : sin0;
        float* __restrict__ sout       = im1 ? sout1 : sout0;
        const int cog = it % NCOG;
        const int pc  = it / NCOG;

        int  ib[PC];
        bool valid[PC];
#pragma unroll
        for (int q = 0; q < PC; q++) {
            int p = pc * PC + q;
            valid[q] = (p < P);
            int pq = valid[q] ? p : 0;
            ib[q] = (pq / WO) * WI + (pq % WO);
        }

        const float4 bv = *(const float4*)(bias + cog * 4);
        float acc[PC][4];
#pragma unroll
        for (int q = 0; q < PC; q++) {
            acc[q][0] = bv.x; acc[q][1] = bv.y; acc[q][2] = bv.z; acc[q][3] = bv.w;
        }

        const float* __restrict__ wp = wt + cog * 4;
        for (int ci = 0; ci < CI; ci++) {
            const float* __restrict__ ip = sin_ + ci * (HI * WI);
#pragma unroll
            for (int r = 0; r < 9; r++) {
                const float4 w = *(const float4*)(wp + (ci * 9 + r) * CO);
                const int off = (r / 3) * WI + (r % 3);
#pragma unroll
                for (int q = 0; q < PC; q++) {
                    float iv = ip[ib[q] + off];
                    acc[q][0] += iv * w.x; acc[q][1] += iv * w.y;
                    acc[q][2] += iv * w.z; acc[q][3] += iv * w.w;
                }
            }
        }

#pragma unroll
        for (int q = 0; q < PC; q++) {
            if (!valid[q]) continue;
            int p = pc * PC + q;
#pragma unroll
            for (int cc = 0; cc < 4; cc++)
                sout[(cog * 4 + cc) * P + p] = fmaxf(acc[q][cc], 0.0f);
        }
    }
}

__global__ __launch_bounds__(256, 3) void conv_stack2(
    const float* __restrict__ states,
    const float* __restrict__ wt0, const float* __restrict__ cb0,
    const float* __restrict__ wt1, const float* __restrict__ cb1,
    const float* __restrict__ wt2, const float* __restrict__ cb2,
    const float* __restrict__ wt3, const float* __restrict__ cb3,
    float* __restrict__ x0)
{
    __shared__ float sA[2][3872];   // input(1800) / L1 out(3872) / L3 out(1568)
    __shared__ float sB[2][2704];   // L0 out(2704) / L2 out(1296)

    const int tid = threadIdx.x;
    const size_t img0 = (size_t)blockIdx.x * 2;

    // stage both images' input (contiguous 3600 floats, float4 coalesced)
    const float* gin = states + img0 * 1800;
    for (int i = tid; i < 900; i += 256) {
        int im = (i >= 450);
        int loc = im ? i - 450 : i;
        *(float4*)(&sA[im][loc * 4]) = *(const float4*)(gin + i * 4);
    }
    __syncthreads();

    conv_layer2<8, 16, 15, 15, 3>(sA[0], sA[1], sB[0], sB[1], wt0, cb0, tid);
    __syncthreads();
    conv_layer2<16, 32, 13, 13, 4>(sB[0], sB[1], sA[0], sA[1], wt1, cb1, tid);
    __syncthreads();
    conv_layer2<32, 16, 11, 11, 3>(sA[0], sA[1], sB[0], sB[1], wt2, cb2, tid);
    __syncthreads();
    conv_layer2<16, 32, 9, 9, 4>(sB[0], sB[1], sA[0], sA[1], wt3, cb3, tid);
    __syncthreads();

    // coalesced copy-out: 2 x 1568 floats contiguous
    float* gout = x0 + img0 * 1568;
    for (int i = tid; i < 784; i += 256) {
        int im = (i >= 392);
        int loc = im ? i - 392 : i;
        *(float4*)(gout + i * 4) = *(const float4*)(&sA[im][loc * 4]);
    }
}

// ---------------------------------------------------------------------------
// GEMM: C[M x 128] = A[M x K] @ W[K x 128] (+bias)(+relu); M-tile 64
// ---------------------------------------------------------------------------
template<int K, bool RELU>
__global__ __launch_bounds__(256) void gemm128(
    const float* __restrict__ Am, const float* __restrict__ Wm,
    const float* __restrict__ bias, float* __restrict__ Cm)
{
    __shared__ float As[64 * 36];    // pad 32->36 keeps 16B alignment
    __shared__ float Ws[32 * 128];

    const int tid = threadIdx.x;
    const int m0  = blockIdx.x * 64;
    const int rg  = tid >> 4;        // 0..15 row group (4 rows)
    const int cg  = tid & 15;        // 0..15 col group (8 cols)

    float acc[4][8];
#pragma unroll
    for (int r = 0; r < 4; r++)
#pragma unroll
        for (int c = 0; c < 8; c++) acc[r][c] = 0.0f;

    for (int k0 = 0; k0 < K; k0 += 32) {
        __syncthreads();
#pragma unroll
        for (int it = 0; it < 2; it++) {
            int idx = tid + it * 256;          // 0..511
            int row = idx >> 3;
            int c4  = idx & 7;
            float4 v = *(const float4*)(Am + (size_t)(m0 + row) * K + k0 + c4 * 4);
            *(float4*)(As + row * 36 + c4 * 4) = v;
        }
#pragma unroll
        for (int it = 0; it < 4; it++) {
            int idx = tid + it * 256;          // 0..1023
            int kr  = idx >> 5;
            int c4  = idx & 31;
            float4 v = *(const float4*)(Wm + (size_t)(k0 + kr) * 128 + c4 * 4);
            *(float4*)(Ws + kr * 128 + c4 * 4) = v;
        }
        __syncthreads();

#pragma unroll
        for (int kk = 0; kk < 32; kk++) {
            float a0 = As[(rg * 4 + 0) * 36 + kk];
            float a1 = As[(rg * 4 + 1) * 36 + kk];
            float a2 = As[(rg * 4 + 2) * 36 + kk];
            float a3 = As[(rg * 4 + 3) * 36 + kk];
            float4 w0 = *(const float4*)(Ws + kk * 128 + cg * 8);
            float4 w1 = *(const float4*)(Ws + kk * 128 + cg * 8 + 4);
            acc[0][0] += a0 * w0.x; acc[0][1] += a0 * w0.y; acc[0][2] += a0 * w0.z; acc[0][3] += a0 * w0.w;
            acc[0][4] += a0 * w1.x; acc[0][5] += a0 * w1.y; acc[0][6] += a0 * w1.z; acc[0][7] += a0 * w1.w;
            acc[1][0] += a1 * w0.x; acc[1][1] += a1 * w0.y; acc[1][2] += a1 * w0.z; acc[1][3] += a1 * w0.w;
            acc[1][4] += a1 * w1.x; acc[1][5] += a1 * w1.y; acc[1][6] += a1 * w1.z; acc[1][7] += a1 * w1.w;
            acc[2][0] += a2 * w0.x; acc[2][1] += a2 * w0.y; acc[2][2] += a2 * w0.z; acc[2][3] += a2 * w0.w;
            acc[2][4] += a2 * w1.x; acc[2][5] += a2 * w1.y; acc[2][6] += a2 * w1.z; acc[2][7] += a2 * w1.w;
            acc[3][0] += a3 * w0.x; acc[3][1] += a3 * w0.y; acc[3][2] += a3 * w0.z; acc[3][3] += a3 * w0.w;
            acc[3][4] += a3 * w1.x; acc[3][5] += a3 * w1.y; acc[3][6] += a3 * w1.z; acc[3][7] += a3 * w1.w;
        }
    }

#pragma unroll
    for (int r = 0; r < 4; r++) {
        int row = m0 + rg * 4 + r;
        float v[8];
#pragma unroll
        for (int c = 0; c < 8; c++) {
            float x = acc[r][c];
            if (bias) x += bias[cg * 8 + c];
            if (RELU) x = fmaxf(x, 0.0f);
            v[c] = x;
        }
        float* gp = Cm + (size_t)row * 128 + cg * 8;
        *(float4*)(gp)     = make_float4(v[0], v[1], v[2], v[3]);
        *(float4*)(gp + 4) = make_float4(v[4], v[5], v[6], v[7]);
    }
}

// ---------------------------------------------------------------------------
// GCN aggregation: out[b,j] = dinv_j * sum_i (adj[b,i,j]*dinv_i*xw[b,i]) + gb
// ---------------------------------------------------------------------------
__global__ __launch_bounds__(256) void gcn_agg(
    const float* __restrict__ adj, const float* __restrict__ xw,
    const float* __restrict__ gb, float* __restrict__ outp)
{
    __shared__ float sAdj[64 * 64];
    __shared__ float sXW[64 * 128];
    __shared__ float sDinv[64];

    const int b = blockIdx.x;
    const int tid = threadIdx.x;

    const float* ga = adj + (size_t)b * 4096;
#pragma unroll
    for (int it = 0; it < 4; it++) {
        int idx = tid + it * 256;
        *(float4*)(sAdj + idx * 4) = *(const float4*)(ga + idx * 4);
    }
    const float* gx = xw + (size_t)b * 8192;
#pragma unroll
    for (int it = 0; it < 8; it++) {
        int idx = tid + it * 256;
        *(float4*)(sXW + idx * 4) = *(const float4*)(gx + idx * 4);
    }
    __syncthreads();

    if (tid < 64) {
        float d = 0.0f;
        for (int i = 0; i < 64; i++) d += sAdj[i * 64 + tid];
        sDinv[tid] = (d > 0.0f) ? rsqrtf(d) : 0.0f;
    }
    __syncthreads();

#pragma unroll
    for (int it = 0; it < 8; it++) {
        int idx = tid + it * 256;   // float4 index
        int i = idx >> 5;
        float s = sDinv[i];
        float4 v = *(float4*)(sXW + idx * 4);
        v.x *= s; v.y *= s; v.z *= s; v.w *= s;
        *(float4*)(sXW + idx * 4) = v;
    }
    __syncthreads();

    const int j  = tid >> 2;
    const int eb = (tid & 3) * 32;
    float acc[32];
#pragma unroll
    for (int e = 0; e < 32; e++) acc[e] = 0.0f;

    for (int i = 0; i < 64; i++) {
        float wgt = sAdj[i * 64 + j];
        const float* xp = sXW + i * 128 + eb;
#pragma unroll
        for (int e4 = 0; e4 < 8; e4++) {
            float4 v = *(const float4*)(xp + e4 * 4);
            acc[e4 * 4 + 0] += wgt * v.x;
            acc[e4 * 4 + 1] += wgt * v.y;
            acc[e4 * 4 + 2] += wgt * v.z;
            acc[e4 * 4 + 3] += wgt * v.w;
        }
    }

    const float dj = sDinv[j];
    float* go = outp + ((size_t)b * 64 + j) * 128 + eb;
#pragma unroll
    for (int e4 = 0; e4 < 8; e4++) {
        float4 v;
        v.x = acc[e4 * 4 + 0] * dj + gb[eb + e4 * 4 + 0];
        v.y = acc[e4 * 4 + 1] * dj + gb[eb + e4 * 4 + 1];
        v.z = acc[e4 * 4 + 2] * dj + gb[eb + e4 * 4 + 2];
        v.w = acc[e4 * 4 + 3] * dj + gb[eb + e4 * 4 + 3];
        *(float4*)(go + e4 * 4) = v;
    }
}

// ---------------------------------------------------------------------------
extern "C" void kernel_launch(void* const* d_in, const int* in_sizes, int n_in,
                              void* d_out, int out_size, void* d_ws, size_t ws_size,
                              hipStream_t stream)
{
    const float* states = (const float*)d_in[0];
    const float* adj    = (const float*)d_in[1];
    const float* cw0 = (const float*)d_in[2];  const float* cb0 = (const float*)d_in[3];
    const float* cw1 = (const float*)d_in[4];  const float* cb1 = (const float*)d_in[5];
    const float* cw2 = (const float*)d_in[6];  const float* cb2 = (const float*)d_in[7];
    const float* cw3 = (const float*)d_in[8];  const float* cb3 = (const float*)d_in[9];
    const float* mw0 = (const float*)d_in[10]; const float* mb0 = (const float*)d_in[11];
    const float* mw1 = (const float*)d_in[12]; const float* mb1 = (const float*)d_in[13];
    const float* mw2 = (const float*)d_in[14]; const float* mb2 = (const float*)d_in[15];
    const float* gw  = (const float*)d_in[16]; const float* gb  = (const float*)d_in[17];

    float* ws = (float*)d_ws;
    float* X0 = ws;                                   // 16384*1568 = 25,690,112 floats
    float* Bu = ws + (size_t)25690112;                // 16384*128
    float* Cu = Bu + (size_t)2097152;                 // 16384*128
    float* WT0 = Cu + (size_t)2097152;                // 1152
    float* WT1 = WT0 + 1152;                          // 4608
    float* WT2 = WT1 + 4608;                          // 4608
    float* WT3 = WT2 + 4608;                          // 4608

    float* out = (float*)d_out;

    transpose_w<<<59, 256, 0, stream>>>(cw0, cw1, cw2, cw3, WT0, WT1, WT2, WT3);
    conv_stack2<<<NIMG / 2, 256, 0, stream>>>(states, WT0, cb0, WT1, cb1,
                                              WT2, cb2, WT3, cb3, X0);
    gemm128<1568, true ><<<256, 256, 0, stream>>>(X0, mw0, mb0, Bu);   // H1
    gemm128<128,  true ><<<256, 256, 0, stream>>>(Bu, mw1, mb1, Cu);   // H2
    gemm128<128,  false><<<256, 256, 0, stream>>>(Cu, mw2, mb2, Bu);   // feats
    gemm128<128,  false><<<256, 256, 0, stream>>>(Bu, gw, nullptr, Cu);// xw
    gcn_agg<<<256, 256, 0, stream>>>(adj, Cu, gb, out);
}

// Round 4
// 1072.912 us; speedup vs baseline: 2.3604x; 1.0978x over previous
//
#include <hip/hip_runtime.h>

// MultiGNN: B=256, A=64 -> 16384 images of 8x15x15
// convs: 8->16 (15->13), 16->32 (13->11), 32->16 (11->9), 16->32 (9->7)
// flatten 32*7*7=1568 -> MLP 128,128,128 -> GCN over 64 agents, E=128
//
// Conv kernel: 2 images/block, all activations in a 61.4KB aliased LDS arena.
// One item = (co-group, out-row [, ci-half]); inner loop reads the input row
// window once per (ci,ky) as 3-4 ds_read_b128 and reuses across kx -> ~6x
// fewer LDS ops per FMA than scalar-read version (which was LDS-pipe-bound).

#define NIMG 16384

// ---------------- LDS arena layout (floats) --------------------------------
// IN     @0      : 2 x 2400  (8ch x 15rows x stride20)
// L0OUT  @8448   : 2 x 3328  (16ch x 13 x stride16)
// L1OUT  @0      : 2 x 4224  (32ch x 11 x stride12)   (input dead)
// L2OUT  @8448   : 2 x 1728  (16ch x 9 x stride12)    (L0OUT dead)
// L2PART @11904  : 2 x 1728
// L3OUT  @0      : 2 x 1568  (flat 32x7x7)            (L1OUT dead)
// L3PART @3136   : 2 x 1568
#define ARENA_F 15360
#define OFF_IN    0
#define OFF_L0    8448
#define OFF_L1    0
#define OFF_L2    8448
#define OFF_L2P   11904
#define OFF_L3    0
#define OFF_L3P   3136

// ---------------------------------------------------------------------------
// One-time weight transpose: wt[l][r][co] = cw[l][co][r], r = ci*9+ky*3+kx
// ---------------------------------------------------------------------------
__global__ __launch_bounds__(256) void transpose_w(
    const float* __restrict__ c0, const float* __restrict__ c1,
    const float* __restrict__ c2, const float* __restrict__ c3,
    float* __restrict__ w0, float* __restrict__ w1,
    float* __restrict__ w2, float* __restrict__ w3)
{
    int g = blockIdx.x * 256 + threadIdx.x;
    const float* src; float* dst; int CI9, CO, loc;
    if (g < 1152)       { src = c0; dst = w0; CI9 = 72;  CO = 16; loc = g; }
    else if (g < 5760)  { src = c1; dst = w1; CI9 = 144; CO = 32; loc = g - 1152; }
    else if (g < 10368) { src = c2; dst = w2; CI9 = 288; CO = 16; loc = g - 5760; }
    else if (g < 14976) { src = c3; dst = w3; CI9 = 144; CO = 32; loc = g - 10368; }
    else return;
    int r = loc / CO, co = loc - r * CO;
    dst[loc] = src[co * CI9 + r];
}

// ---------------------------------------------------------------------------
// Generic row-conv pass.
// item = cog + NCOG*(chunk + NCHUNK*(y + HO*(half + NSPLIT*img)))
// SLOTS output positions per item starting at x0 = chunk*X0STEP.
// Per (ci,ky): NREAD4 ds_read_b128 cover the input row window, reused over kx.
// NSPLIT==2: half0 -> sOut0 (bias-init), half1 -> sOutP (zero-init), no relu
// (combined later). NSPLIT==1: bias + relu here.
// ---------------------------------------------------------------------------
template<int CI_SUB, int CO, int HO, int WO, int SLOTS, int X0STEP, int NCHUNK,
         int NSPLIT, int IN_RS, int IN_PLANE, int IN_IMG,
         int OUT_RS, int OUT_PLANE, int OUT_IMG, int NREAD4>
__device__ __forceinline__ void conv_row(
    const float* __restrict__ sIn, float* __restrict__ sOut0,
    float* __restrict__ sOutP, const float* __restrict__ wt,
    const float* __restrict__ bias, int tid)
{
    constexpr int NCOG = CO / 4;
    constexpr int NITEMS = NCOG * NCHUNK * HO * NSPLIT * 2;
    static_assert(NITEMS <= 256, "single pass");
    if (tid >= NITEMS) return;

    int item = tid;
    const int cog = item % NCOG;          item /= NCOG;
    const int chunk = item % NCHUNK;      item /= NCHUNK;
    const int y = item % HO;              item /= HO;
    const int half = item % NSPLIT;       item /= NSPLIT;
    const int img = item;
    const int x0 = chunk * X0STEP;
    const int ci0 = half * CI_SUB;

    float* __restrict__ sOut = (half == 0) ? sOut0 : sOutP;

    float acc[SLOTS][4];
    if (half == 0) {
        const float4 bv = *(const float4*)(bias + cog * 4);
#pragma unroll
        for (int q = 0; q < SLOTS; q++) {
            acc[q][0] = bv.x; acc[q][1] = bv.y; acc[q][2] = bv.z; acc[q][3] = bv.w;
        }
    } else {
#pragma unroll
        for (int q = 0; q < SLOTS; q++)
            acc[q][0] = acc[q][1] = acc[q][2] = acc[q][3] = 0.0f;
    }

    const float* __restrict__ inBase = sIn + img * IN_IMG + y * IN_RS + x0;
    const float* __restrict__ wBase  = wt + cog * 4;

#pragma unroll 1
    for (int ci = 0; ci < CI_SUB; ci++) {
        const float* __restrict__ ip = inBase + (ci0 + ci) * IN_PLANE;
        const float* __restrict__ wp = wBase + (ci0 + ci) * 9 * CO;
#pragma unroll
        for (int ky = 0; ky < 3; ky++) {
            union { float4 v4[NREAD4]; float xs[NREAD4 * 4]; } xv;
            const float* __restrict__ rp = ip + ky * IN_RS;
#pragma unroll
            for (int j = 0; j < NREAD4; j++)
                xv.v4[j] = *(const float4*)(rp + j * 4);
            float4 w[3];
#pragma unroll
            for (int kx = 0; kx < 3; kx++)
                w[kx] = *(const float4*)(wp + (ky * 3 + kx) * CO);
#pragma unroll
            for (int kx = 0; kx < 3; kx++) {
#pragma unroll
                for (int q = 0; q < SLOTS; q++) {
                    const float iv = xv.xs[q + kx];
                    acc[q][0] += iv * w[kx].x; acc[q][1] += iv * w[kx].y;
                    acc[q][2] += iv * w[kx].z; acc[q][3] += iv * w[kx].w;
                }
            }
        }
    }

    float* __restrict__ op = sOut + img * OUT_IMG + y * OUT_RS + x0;
#pragma unroll
    for (int q = 0; q < SLOTS; q++) {
        if (x0 + q >= WO) break;
#pragma unroll
        for (int cc = 0; cc < 4; cc++) {
            float v = acc[q][cc];
            if (NSPLIT == 1) v = fmaxf(v, 0.0f);
            op[(cog * 4 + cc) * OUT_PLANE + q] = v;
        }
    }
}

__global__ __launch_bounds__(256, 2) void conv_stack3(
    const float* __restrict__ states,
    const float* __restrict__ wt0, const float* __restrict__ cb0,
    const float* __restrict__ wt1, const float* __restrict__ cb1,
    const float* __restrict__ wt2, const float* __restrict__ cb2,
    const float* __restrict__ wt3, const float* __restrict__ cb3,
    float* __restrict__ x0out)
{
    __shared__ float A[ARENA_F];
    const int tid = threadIdx.x;

    // ---- stage input with row re-pad 15 -> stride 20 ----
    const float* gin = states + (size_t)blockIdx.x * 3600;
    for (int e = tid; e < 3600; e += 256) {
        int img = e / 1800, r = e - img * 1800;
        int ci = r / 225;  r -= ci * 225;
        int y = r / 15, x = r - y * 15;
        A[OFF_IN + img * 2400 + ci * 300 + y * 20 + x] = gin[e];
    }
    __syncthreads();

    // L0: 8->16, 15->13.  2 chunks (x0=0,8), SLOTS=8.  in rs20/pl300, out rs16/pl208
    conv_row<8, 16, 13, 13, 8, 8, 2, 1, 20, 300, 2400, 16, 208, 3328, 3>(
        A + OFF_IN, A + OFF_L0, A + OFF_L0, wt0, cb0, tid);
    __syncthreads();

    // L1: 16->32, 13->11.  full row SLOTS=11.  in rs16/pl208, out rs12/pl132
    conv_row<16, 32, 11, 11, 11, 0, 1, 1, 16, 208, 3328, 12, 132, 4224, 4>(
        A + OFF_L0, A + OFF_L1, A + OFF_L1, wt1, cb1, tid);
    __syncthreads();

    // L2: 32->16, 11->9.  ci-split x2, SLOTS=9.  in rs12/pl132, out rs12/pl108
    conv_row<16, 16, 9, 9, 9, 0, 1, 2, 12, 132, 4224, 12, 108, 1728, 3>(
        A + OFF_L1, A + OFF_L2, A + OFF_L2P, wt2, cb2, tid);
    __syncthreads();
    // combine halves + relu (in place)
    for (int i = tid; i < 3456; i += 256) {
        float v = A[OFF_L2 + i] + A[OFF_L2P + i];
        A[OFF_L2 + i] = fmaxf(v, 0.0f);
    }
    __syncthreads();

    // L3: 16->32, 9->7.  ci-split x2, SLOTS=7, flat out (stride7/plane49)
    conv_row<8, 32, 7, 7, 7, 0, 1, 2, 12, 108, 1728, 7, 49, 1568, 3>(
        A + OFF_L2, A + OFF_L3, A + OFF_L3P, wt3, cb3, tid);
    __syncthreads();

    // combine + relu + coalesced global store (flat [img][32*7*7])
    float* gout = x0out + (size_t)blockIdx.x * 3136;
    for (int i = tid; i < 3136; i += 256) {
        float v = A[OFF_L3 + i] + A[OFF_L3P + i];
        gout[i] = fmaxf(v, 0.0f);
    }
}

// ---------------------------------------------------------------------------
// GEMM: C[M x 128] = A[M x K] @ W[K x 128] (+bias)(+relu); M-tile 64
// ---------------------------------------------------------------------------
template<int K, bool RELU>
__global__ __launch_bounds__(256) void gemm128(
    const float* __restrict__ Am, const float* __restrict__ Wm,
    const float* __restrict__ bias, float* __restrict__ Cm)
{
    __shared__ float As[64 * 36];
    __shared__ float Ws[32 * 128];

    const int tid = threadIdx.x;
    const int m0  = blockIdx.x * 64;
    const int rg  = tid >> 4;
    const int cg  = tid & 15;

    float acc[4][8];
#pragma unroll
    for (int r = 0; r < 4; r++)
#pragma unroll
        for (int c = 0; c < 8; c++) acc[r][c] = 0.0f;

    for (int k0 = 0; k0 < K; k0 += 32) {
        __syncthreads();
#pragma unroll
        for (int it = 0; it < 2; it++) {
            int idx = tid + it * 256;
            int row = idx >> 3;
            int c4  = idx & 7;
            float4 v = *(const float4*)(Am + (size_t)(m0 + row) * K + k0 + c4 * 4);
            *(float4*)(As + row * 36 + c4 * 4) = v;
        }
#pragma unroll
        for (int it = 0; it < 4; it++) {
            int idx = tid + it * 256;
            int kr  = idx >> 5;
            int c4  = idx & 31;
            float4 v = *(const float4*)(Wm + (size_t)(k0 + kr) * 128 + c4 * 4);
            *(float4*)(Ws + kr * 128 + c4 * 4) = v;
        }
        __syncthreads();

#pragma unroll
        for (int kk = 0; kk < 32; kk++) {
            float a0 = As[(rg * 4 + 0) * 36 + kk];
            float a1 = As[(rg * 4 + 1) * 36 + kk];
            float a2 = As[(rg * 4 + 2) * 36 + kk];
            float a3 = As[(rg * 4 + 3) * 36 + kk];
            float4 w0 = *(const float4*)(Ws + kk * 128 + cg * 8);
            float4 w1 = *(const float4*)(Ws + kk * 128 + cg * 8 + 4);
            acc[0][0] += a0 * w0.x; acc[0][1] += a0 * w0.y; acc[0][2] += a0 * w0.z; acc[0][3] += a0 * w0.w;
            acc[0][4] += a0 * w1.x; acc[0][5] += a0 * w1.y; acc[0][6] += a0 * w1.z; acc[0][7] += a0 * w1.w;
            acc[1][0] += a1 * w0.x; acc[1][1] += a1 * w0.y; acc[1][2] += a1 * w0.z; acc[1][3] += a1 * w0.w;
            acc[1][4] += a1 * w1.x; acc[1][5] += a1 * w1.y; acc[1][6] += a1 * w1.z; acc[1][7] += a1 * w1.w;
            acc[2][0] += a2 * w0.x; acc[2][1] += a2 * w0.y; acc[2][2] += a2 * w0.z; acc[2][3] += a2 * w0.w;
            acc[2][4] += a2 * w1.x; acc[2][5] += a2 * w1.y; acc[2][6] += a2 * w1.z; acc[2][7] += a2 * w1.w;
            acc[3][0] += a3 * w0.x; acc[3][1] += a3 * w0.y; acc[3][2] += a3 * w0.z; acc[3][3] += a3 * w0.w;
            acc[3][4] += a3 * w1.x; acc[3][5] += a3 * w1.y; acc[3][6] += a3 * w1.z; acc[3][7] += a3 * w1.w;
        }
    }

#pragma unroll
    for (int r = 0; r < 4; r++) {
        int row = m0 + rg * 4 + r;
        float v[8];
#pragma unroll
        for (int c = 0; c < 8; c++) {
            float x = acc[r][c];
            if (bias) x += bias[cg * 8 + c];
            if (RELU) x = fmaxf(x, 0.0f);
            v[c] = x;
        }
        float* gp = Cm + (size_t)row * 128 + cg * 8;
        *(float4*)(gp)     = make_float4(v[0], v[1], v[2], v[3]);
        *(float4*)(gp + 4) = make_float4(v[4], v[5], v[6], v[7]);
    }
}

// ---------------------------------------------------------------------------
// GCN aggregation: out[b,j] = dinv_j * sum_i (adj[b,i,j]*dinv_i*xw[b,i]) + gb
// ---------------------------------------------------------------------------
__global__ __launch_bounds__(256) void gcn_agg(
    const float* __restrict__ adj, const float* __restrict__ xw,
    const float* __restrict__ gb, float* __restrict__ outp)
{
    __shared__ float sAdj[64 * 64];
    __shared__ float sXW[64 * 128];
    __shared__ float sDinv[64];

    const int b = blockIdx.x;
    const int tid = threadIdx.x;

    const float* ga = adj + (size_t)b * 4096;
#pragma unroll
    for (int it = 0; it < 4; it++) {
        int idx = tid + it * 256;
        *(float4*)(sAdj + idx * 4) = *(const float4*)(ga + idx * 4);
    }
    const float* gx = xw + (size_t)b * 8192;
#pragma unroll
    for (int it = 0; it < 8; it++) {
        int idx = tid + it * 256;
        *(float4*)(sXW + idx * 4) = *(const float4*)(gx + idx * 4);
    }
    __syncthreads();

    if (tid < 64) {
        float d = 0.0f;
        for (int i = 0; i < 64; i++) d += sAdj[i * 64 + tid];
        sDinv[tid] = (d > 0.0f) ? rsqrtf(d) : 0.0f;
    }
    __syncthreads();

#pragma unroll
    for (int it = 0; it < 8; it++) {
        int idx = tid + it * 256;
        int i = idx >> 5;
        float s = sDinv[i];
        float4 v = *(float4*)(sXW + idx * 4);
        v.x *= s; v.y *= s; v.z *= s; v.w *= s;
        *(float4*)(sXW + idx * 4) = v;
    }
    __syncthreads();

    const int j  = tid >> 2;
    const int eb = (tid & 3) * 32;
    float acc[32];
#pragma unroll
    for (int e = 0; e < 32; e++) acc[e] = 0.0f;

    for (int i = 0; i < 64; i++) {
        float wgt = sAdj[i * 64 + j];
        const float* xp = sXW + i * 128 + eb;
#pragma unroll
        for (int e4 = 0; e4 < 8; e4++) {
            float4 v = *(const float4*)(xp + e4 * 4);
            acc[e4 * 4 + 0] += wgt * v.x;
            acc[e4 * 4 + 1] += wgt * v.y;
            acc[e4 * 4 + 2] += wgt * v.z;
            acc[e4 * 4 + 3] += wgt * v.w;
        }
    }

    const float dj = sDinv[j];
    float* go = outp + ((size_t)b * 64 + j) * 128 + eb;
#pragma unroll
    for (int e4 = 0; e4 < 8; e4++) {
        float4 v;
        v.x = acc[e4 * 4 + 0] * dj + gb[eb + e4 * 4 + 0];
        v.y = acc[e4 * 4 + 1] * dj + gb[eb + e4 * 4 + 1];
        v.z = acc[e4 * 4 + 2] * dj + gb[eb + e4 * 4 + 2];
        v.w = acc[e4 * 4 + 3] * dj + gb[eb + e4 * 4 + 3];
        *(float4*)(go + e4 * 4) = v;
    }
}

// ---------------------------------------------------------------------------
extern "C" void kernel_launch(void* const* d_in, const int* in_sizes, int n_in,
                              void* d_out, int out_size, void* d_ws, size_t ws_size,
                              hipStream_t stream)
{
    const float* states = (const float*)d_in[0];
    const float* adj    = (const float*)d_in[1];
    const float* cw0 = (const float*)d_in[2];  const float* cb0 = (const float*)d_in[3];
    const float* cw1 = (const float*)d_in[4];  const float* cb1 = (const float*)d_in[5];
    const float* cw2 = (const float*)d_in[6];  const float* cb2 = (const float*)d_in[7];
    const float* cw3 = (const float*)d_in[8];  const float* cb3 = (const float*)d_in[9];
    const float* mw0 = (const float*)d_in[10]; const float* mb0 = (const float*)d_in[11];
    const float* mw1 = (const float*)d_in[12]; const float* mb1 = (const float*)d_in[13];
    const float* mw2 = (const float*)d_in[14]; const float* mb2 = (const float*)d_in[15];
    const float* gw  = (const float*)d_in[16]; const float* gb  = (const float*)d_in[17];

    float* ws = (float*)d_ws;
    float* X0 = ws;                                   // 16384*1568 floats
    float* Bu = ws + (size_t)25690112;                // 16384*128
    float* Cu = Bu + (size_t)2097152;                 // 16384*128
    float* WT0 = Cu + (size_t)2097152;                // 1152
    float* WT1 = WT0 + 1152;                          // 4608
    float* WT2 = WT1 + 4608;                          // 4608
    float* WT3 = WT2 + 4608;                          // 4608

    float* out = (float*)d_out;

    transpose_w<<<59, 256, 0, stream>>>(cw0, cw1, cw2, cw3, WT0, WT1, WT2, WT3);
    conv_stack3<<<NIMG / 2, 256, 0, stream>>>(states, WT0, cb0, WT1, cb1,
                                              WT2, cb2, WT3, cb3, X0);
    gemm128<1568, true ><<<256, 256, 0, stream>>>(X0, mw0, mb0, Bu);   // H1
    gemm128<128,  true ><<<256, 256, 0, stream>>>(Bu, mw1, mb1, Cu);   // H2
    gemm128<128,  false><<<256, 256, 0, stream>>>(Cu, mw2, mb2, Bu);   // feats
    gemm128<128,  false><<<256, 256, 0, stream>>>(Bu, gw, nullptr, Cu);// xw
    gcn_agg<<<256, 256, 0, stream>>>(adj, Cu, gb, out);
}